// Round 1
// baseline (243.145 us; speedup 1.0000x reference)
//
#include <hip/hip_runtime.h>
#include <float.h>
#include <stdint.h>

// StatisticExtractor: B=128, C=32, L=8192.
// out[b, s*32 + c], s in {mean,std,max,min,q25,q75,dmean,dstd,energy,rms}.
// One 256-thread block per (b,c) row. Row staged in LDS (invalid -> FLT_MAX,
// matching the reference's fmax sentinel). Exact quantiles via monotone
// histogram select + radix-select fallback.

#define L_LEN 8192
#define NT 256
#define NB 1024   // histogram bins for quantile select
#define CAP 256   // max gathered candidates per target bin

__global__ __launch_bounds__(NT, 4)
void stats_kernel(const float* __restrict__ data,
                  const int* __restrict__ mask,
                  float* __restrict__ out)
{
    __shared__ __align__(16) float s_val[L_LEN];   // 32 KB
    __shared__ uint32_t s_hist[NB];                // 4 KB (reused: scan array, gather bufs)
    __shared__ float s_red[32];                    // 8 quantities x 4 waves
    __shared__ float s_fstat[6];
    __shared__ int   s_istat[2];
    __shared__ int   s_tbin[4], s_tbelow[4], s_tcnt[4];
    __shared__ int   s_gcnt[4];
    __shared__ float s_qv[4];
    __shared__ int   s_sel[2];

    const int tid = threadIdx.x;
    const int bid = blockIdx.x;
    const int b = bid >> 5;          // C == 32
    const int c = bid & 31;

    const float* row  = data + (size_t)bid * L_LEN;
    const int*   mrow = mask + (size_t)b  * L_LEN;

    // ---------------- Phase A: coalesced load, mask -> sentinel, stage ----------------
    for (int i = tid * 4; i < L_LEN; i += NT * 4) {
        const float4 v = *reinterpret_cast<const float4*>(row + i);
        const int4   m = *reinterpret_cast<const int4*>(mrow + i);
        float4 w;
        w.x = m.x ? v.x : FLT_MAX;
        w.y = m.y ? v.y : FLT_MAX;
        w.z = m.z ? v.z : FLT_MAX;
        w.w = m.w ? v.w : FLT_MAX;
        *reinterpret_cast<float4*>(&s_val[i]) = w;
    }
    __syncthreads();

    // ---------------- Phase B: masked stats + first-difference stats ----------------
    float sum = 0.f, sumsq = 0.f, dsum = 0.f, dsumsq = 0.f;
    float mn = FLT_MAX, mx = -FLT_MAX;
    int cnt = 0, dcnt = 0;

    for (int i4 = tid; i4 < L_LEN / 4; i4 += NT) {
        const float4 v = *reinterpret_cast<const float4*>(&s_val[i4 * 4]);
        // element 4*i4+4 = next thread's v.x (same iteration), except at wave edge
        float nxt = __shfl_down(v.x, 1, 64);
        if ((tid & 63) == 63) {
            nxt = (i4 * 4 + 4 < L_LEN) ? s_val[i4 * 4 + 4] : FLT_MAX;
        }
#define DO_ELEM(X, Y) do {                                                    \
            float x_ = (X);                                                   \
            if (x_ != FLT_MAX) {                                              \
                sum += x_; sumsq += x_ * x_;                                  \
                mn = fminf(mn, x_); mx = fmaxf(mx, x_); ++cnt;                \
                float y_ = (Y);                                               \
                if (y_ != FLT_MAX) {                                          \
                    float d_ = y_ - x_; dsum += d_; dsumsq += d_ * d_; ++dcnt;\
                }                                                             \
            }                                                                 \
        } while (0)
        DO_ELEM(v.x, v.y);
        DO_ELEM(v.y, v.z);
        DO_ELEM(v.z, v.w);
        DO_ELEM(v.w, nxt);
#undef DO_ELEM
    }

    // block reduction: wave shuffle then cross-wave via LDS
#pragma unroll
    for (int off = 32; off > 0; off >>= 1) {
        sum    += __shfl_down(sum, off, 64);
        sumsq  += __shfl_down(sumsq, off, 64);
        dsum   += __shfl_down(dsum, off, 64);
        dsumsq += __shfl_down(dsumsq, off, 64);
        mn = fminf(mn, __shfl_down(mn, off, 64));
        mx = fmaxf(mx, __shfl_down(mx, off, 64));
        cnt  += __shfl_down(cnt, off, 64);
        dcnt += __shfl_down(dcnt, off, 64);
    }
    const int wid = tid >> 6;
    if ((tid & 63) == 0) {
        s_red[0 * 4 + wid] = sum;
        s_red[1 * 4 + wid] = sumsq;
        s_red[2 * 4 + wid] = dsum;
        s_red[3 * 4 + wid] = dsumsq;
        s_red[4 * 4 + wid] = mn;
        s_red[5 * 4 + wid] = mx;
        s_red[6 * 4 + wid] = __int_as_float(cnt);
        s_red[7 * 4 + wid] = __int_as_float(dcnt);
    }
    __syncthreads();
    if (tid == 0) {
        float S = 0.f, SQ = 0.f, DS = 0.f, DSQ = 0.f;
        float MN = FLT_MAX, MX = -FLT_MAX;
        int CN = 0, DC = 0;
        for (int w = 0; w < 4; ++w) {
            S  += s_red[0 * 4 + w];
            SQ += s_red[1 * 4 + w];
            DS += s_red[2 * 4 + w];
            DSQ+= s_red[3 * 4 + w];
            MN = fminf(MN, s_red[4 * 4 + w]);
            MX = fmaxf(MX, s_red[5 * 4 + w]);
            CN += __float_as_int(s_red[6 * 4 + w]);
            DC += __float_as_int(s_red[7 * 4 + w]);
        }
        s_fstat[0] = S; s_fstat[1] = SQ; s_fstat[2] = DS; s_fstat[3] = DSQ;
        s_fstat[4] = MN; s_fstat[5] = MX;
        s_istat[0] = CN; s_istat[1] = DC;
    }
    __syncthreads();

    const float tsum = s_fstat[0], tsumsq = s_fstat[1];
    const float tdsum = s_fstat[2], tdsumsq = s_fstat[3];
    const float tmn = s_fstat[4], tmx = s_fstat[5];
    const int n = s_istat[0], nd = s_istat[1];

    // ---------------- Phase C: exact q25 / q75 ----------------
    float q25 = 0.f, q75 = 0.f;
    if (n > 0 && tmn == tmx) {
        q25 = q75 = tmn;                    // all valid values identical (or n==1)
    } else if (n > 0) {
        const float pos25 = 0.25f * (float)(n - 1);
        const float pos75 = 0.75f * (float)(n - 1);
        const int l25 = (int)floorf(pos25), h25 = (int)ceilf(pos25);
        const int l75 = (int)floorf(pos75), h75 = (int)ceilf(pos75);
        const float frac25 = pos25 - (float)l25;
        const float frac75 = pos75 - (float)l75;
        int ranks[4] = { l25, h25, l75, h75 };

        // 1) histogram over [tmn, tmx]; binning is weakly monotone in x -> exact ranks
        for (int j = tid; j < NB; j += NT) s_hist[j] = 0u;
        __syncthreads();
        const float scale = (float)NB / (tmx - tmn);
        for (int i4 = tid; i4 < L_LEN / 4; i4 += NT) {
            const float4 v = *reinterpret_cast<const float4*>(&s_val[i4 * 4]);
#define DO_H(X) do {                                                          \
                float x_ = (X);                                               \
                if (x_ != FLT_MAX) {                                          \
                    int bn_ = (int)((x_ - tmn) * scale);                      \
                    bn_ = bn_ < 0 ? 0 : (bn_ > NB - 1 ? NB - 1 : bn_);        \
                    atomicAdd(&s_hist[bn_], 1u);                              \
                }                                                             \
            } while (0)
            DO_H(v.x); DO_H(v.y); DO_H(v.z); DO_H(v.w);
#undef DO_H
        }
        __syncthreads();

        // 2) block scan: each thread owns 4 bins
        uint32_t cl[4];
        uint32_t lt = 0;
        const int base4 = tid * 4;
#pragma unroll
        for (int j = 0; j < 4; ++j) { cl[j] = s_hist[base4 + j]; lt += cl[j]; }
        __syncthreads();
        s_hist[tid] = lt;
        __syncthreads();
        for (int off = 1; off < NT; off <<= 1) {
            uint32_t vv = s_hist[tid];
            uint32_t add = (tid >= off) ? s_hist[tid - off] : 0u;
            __syncthreads();
            s_hist[tid] = vv + add;
            __syncthreads();
        }
        const uint32_t inclT = s_hist[tid];
        uint32_t run = inclT - lt;          // exclusive prefix for this thread's bins
#pragma unroll
        for (int j = 0; j < 4; ++j) {
            const uint32_t excl = run, incl = run + cl[j];
            for (int t = 0; t < 4; ++t) {
                const uint32_t r = (uint32_t)ranks[t];
                if (r >= excl && r < incl) {
                    s_tbin[t] = base4 + j;
                    s_tbelow[t] = (int)excl;
                    s_tcnt[t] = (int)cl[j];
                }
            }
            run = incl;
        }
        if (tid < 4) s_gcnt[tid] = 0;
        __syncthreads();

        // 3) gather candidates of the (<=4) target bins
        float* gbuf = reinterpret_cast<float*>(s_hist);   // 4 x CAP floats = 4 KB
        const int tb0 = s_tbin[0], tb1 = s_tbin[1], tb2 = s_tbin[2], tb3 = s_tbin[3];
        for (int i4 = tid; i4 < L_LEN / 4; i4 += NT) {
            const float4 v = *reinterpret_cast<const float4*>(&s_val[i4 * 4]);
#define DO_G(X) do {                                                          \
                float x_ = (X);                                               \
                if (x_ != FLT_MAX) {                                          \
                    int bn_ = (int)((x_ - tmn) * scale);                      \
                    bn_ = bn_ < 0 ? 0 : (bn_ > NB - 1 ? NB - 1 : bn_);        \
                    if (bn_ == tb0) { int i_ = atomicAdd(&s_gcnt[0], 1); if (i_ < CAP) gbuf[0 * CAP + i_] = x_; } \
                    if (bn_ == tb1) { int i_ = atomicAdd(&s_gcnt[1], 1); if (i_ < CAP) gbuf[1 * CAP + i_] = x_; } \
                    if (bn_ == tb2) { int i_ = atomicAdd(&s_gcnt[2], 1); if (i_ < CAP) gbuf[2 * CAP + i_] = x_; } \
                    if (bn_ == tb3) { int i_ = atomicAdd(&s_gcnt[3], 1); if (i_ < CAP) gbuf[3 * CAP + i_] = x_; } \
                }                                                             \
            } while (0)
            DO_G(v.x); DO_G(v.y); DO_G(v.z); DO_G(v.w);
#undef DO_G
        }
        __syncthreads();

        // 4) counting-rank selection inside each gathered bin (k expected ~13)
        for (int t = 0; t < 4; ++t) {
            const int k = s_tcnt[t];
            if (k <= CAP) {
                const int rin = ranks[t] - s_tbelow[t];
                if (tid < k) {
                    const float xi = gbuf[t * CAP + tid];
                    int cless = 0;
                    for (int j = 0; j < k; ++j) {
                        const float y = gbuf[t * CAP + j];
                        cless += (y < xi || (y == xi && j < tid)) ? 1 : 0;
                    }
                    if (cless == rin) s_qv[t] = xi;
                }
            }
        }
        __syncthreads();

        // 5) exact radix-select fallback for any bin that overflowed CAP
        //    (never triggered for spread data; guarantees correctness)
        for (int t = 0; t < 4; ++t) {
            if (s_tcnt[t] > CAP) {
                uint32_t prefix = 0u, pmask = 0u;
                int r = ranks[t];
                for (int shift = 24; shift >= 0; shift -= 8) {
                    s_hist[tid] = 0u;
                    __syncthreads();
                    for (int i4 = tid; i4 < L_LEN / 4; i4 += NT) {
                        const float4 v = *reinterpret_cast<const float4*>(&s_val[i4 * 4]);
#define DO_R(X) do {                                                          \
                            uint32_t u_ = __float_as_uint(X);                 \
                            uint32_t k_ = (u_ & 0x80000000u) ? ~u_ : (u_ | 0x80000000u); \
                            if ((k_ & pmask) == prefix)                       \
                                atomicAdd(&s_hist[(k_ >> shift) & 0xFFu], 1u);\
                        } while (0)
                        DO_R(v.x); DO_R(v.y); DO_R(v.z); DO_R(v.w);
#undef DO_R
                    }
                    __syncthreads();
                    const uint32_t cb = s_hist[tid];
                    __syncthreads();
                    s_hist[tid] = cb;
                    __syncthreads();
                    for (int off = 1; off < NT; off <<= 1) {
                        uint32_t vv = s_hist[tid];
                        uint32_t add = (tid >= off) ? s_hist[tid - off] : 0u;
                        __syncthreads();
                        s_hist[tid] = vv + add;
                        __syncthreads();
                    }
                    const uint32_t incl = s_hist[tid];
                    const uint32_t excl = incl - cb;
                    if ((uint32_t)r >= excl && (uint32_t)r < incl) {
                        s_sel[0] = tid;
                        s_sel[1] = (int)excl;
                    }
                    __syncthreads();
                    prefix |= ((uint32_t)s_sel[0]) << shift;
                    pmask  |= 0xFFu << shift;
                    r -= s_sel[1];
                    __syncthreads();
                }
                if (tid == 0) {
                    const uint32_t u = (prefix & 0x80000000u) ? (prefix ^ 0x80000000u) : ~prefix;
                    s_qv[t] = __uint_as_float(u);
                }
                __syncthreads();
            }
        }
        __syncthreads();

        q25 = s_qv[0] + frac25 * (s_qv[1] - s_qv[0]);
        q75 = s_qv[2] + frac75 * (s_qv[3] - s_qv[2]);
    }
    // n == 0: q25 = q75 = 0 (matches reference's where(n>0, ., 0))

    // ---------------- epilogue ----------------
    if (tid == 0) {
        const float fc = (float)n;
        const float mean = (n > 0) ? tsum / fc : 0.f;
        const float var  = (n > 0) ? fmaxf(tsumsq / fc - mean * mean, 0.f) : 0.f;
        const float stdv = sqrtf(var);
        const float dmean = (nd > 0) ? tdsum / (float)nd : 0.f;
        const float dvar  = (nd > 0) ? fmaxf(tdsumsq / (float)nd - dmean * dmean, 0.f) : 0.f;
        const float dstd  = sqrtf(dvar);
        const float energy = tsumsq;
        const float rms = (n > 0) ? sqrtf(tsumsq / fc) : 0.f;

        float* o = out + (size_t)b * 320 + c;
        o[0 * 32] = mean;
        o[1 * 32] = stdv;
        o[2 * 32] = tmx;     // -FLT_MAX when n==0, matching reference fmin fill
        o[3 * 32] = tmn;     //  FLT_MAX when n==0
        o[4 * 32] = q25;
        o[5 * 32] = q75;
        o[6 * 32] = dmean;
        o[7 * 32] = dstd;
        o[8 * 32] = energy;
        o[9 * 32] = rms;
    }
}

extern "C" void kernel_launch(void* const* d_in, const int* in_sizes, int n_in,
                              void* d_out, int out_size, void* d_ws, size_t ws_size,
                              hipStream_t stream) {
    const float* data = (const float*)d_in[0];
    const int*   mask = (const int*)d_in[1];
    float*       out  = (float*)d_out;
    stats_kernel<<<dim3(128 * 32), dim3(NT), 0, stream>>>(data, mask, out);
}